// Round 2
// baseline (8239.626 us; speedup 1.0000x reference)
//
#include <hip/hip_runtime.h>

typedef _Float16 f16x8 __attribute__((ext_vector_type(8)));
typedef _Float16 f16x4 __attribute__((ext_vector_type(4)));
typedef float f32x4 __attribute__((ext_vector_type(4)));
typedef unsigned long long u64_t;

union FP16U { _Float16 h; unsigned short u; };

__device__ __forceinline__ float sigmoidf_(float x) {
    return __builtin_amdgcn_rcpf(1.f + __expf(-x));
}

__device__ __forceinline__ float tanhf_(float x) {
    float a = fabsf(x);
    float e = __expf(-2.f * a);
    float r = (1.f - e) * __builtin_amdgcn_rcpf(1.f + e);
    return copysignf(r, x);
}

__device__ __forceinline__ f32x4 mfma16(f16x8 a, f16x8 b, f32x4 c) {
    return __builtin_amdgcn_mfma_f32_16x16x32_f16(a, b, c, 0, 0, 0);
}

// ---------------------------------------------------------------------------
// ws layout (bytes):
//   0        : whhA   61440 f16x8 A-fragments (983040 B)
//              frag fr = ((q*6+jc)*2+kh)*20 + fslot ; element = fr*64 + lane
//   983040   : wih2f  2304 f16x8 A-fragments for xp2 (36864 B)
//   1048576  : sxp2   64*2048*48 f32 (25165824 B) — atomic-accumulated
//   26214400 : exch   4 groups * 2 bufs * 3072 u64 tagged h-pairs (196608 B)
// ---------------------------------------------------------------------------
// A-fragment semantics (mfma_f32_16x16x32_f16):
//   lane l: A row = (l&15), k = (l>>4)*8 + i   (8 halves, 4 VGPR)
//   lane l: B col = (l&15), k = (l>>4)*8 + i
//   lane l: C row = (l>>4)*4 + i, col = (l&15)
// K layout (416): k<384 -> h[k]; 384..403 -> x[k-384]; 404..415 -> 0 pad.
// kh0 fslots: 0..6 R kt0..6 | 7..13 Z kt0..6 | 14..19 HN kt0..5
// kh1 fslots: 0..5 R kt7..12 | 6..11 Z kt7..12 | 12..17 HN kt6..11 | 18 XN kt12

__global__ void pack_weights(const float* __restrict__ Whh1,
                             const float* __restrict__ Wih1,
                             const float* __restrict__ Wih2,
                             _Float16* __restrict__ wsbase) {
    int tid = blockIdx.x * 256 + threadIdx.x;
    f16x8* whhA  = (f16x8*)wsbase;
    f16x8* wih2f = (f16x8*)(wsbase + 491520);
    if (tid < 61440) {
        int l = tid & 63, fr = tid >> 6;
        int fslot = fr % 20, w = fr / 20;
        int kh = w & 1, jq = w >> 1;
        int jc = jq % 6, q = jq / 6;
        int tile, kt;  // 0=R 1=Z 2=HN 3=XN 4=pad
        if (kh == 0) {
            if (fslot < 7)       { tile = 0; kt = fslot; }
            else if (fslot < 14) { tile = 1; kt = fslot - 7; }
            else                 { tile = 2; kt = fslot - 14; }
        } else {
            if (fslot < 6)       { tile = 0; kt = 7 + fslot; }
            else if (fslot < 12) { tile = 1; kt = 1 + fslot; }
            else if (fslot < 18) { tile = 2; kt = fslot - 6; }
            else if (fslot == 18){ tile = 3; kt = 12; }
            else                 { tile = 4; kt = 0; }
        }
        int gate = (tile == 0) ? 0 : (tile == 1) ? 1 : 2;
        int row = gate * 384 + q * 96 + jc * 16 + (l & 15);
        int k0 = kt * 32 + (l >> 4) * 8;
        f16x8 v;
#pragma unroll
        for (int i = 0; i < 8; ++i) {
            float f = 0.f;
            if (tile != 4) {
                int k = k0 + i;
                if (tile == 3) {
                    int kx = k - 384;
                    f = (kx < 20) ? Wih1[row * 20 + kx] : 0.f;
                } else if (k < 384) {
                    f = Whh1[row * 384 + k];
                } else if (tile < 2) {
                    int kx = k - 384;
                    f = (kx < 20) ? Wih1[row * 20 + kx] : 0.f;
                }
            }
            v[i] = (_Float16)f;
        }
        whhA[tid] = v;
    } else if (tid < 63744) {
        int t2 = tid - 61440;
        int l = t2 & 63, fi = t2 >> 6;   // fi = q*9 + v
        int q = fi / 9, vv = fi % 9;
        int Mt = vv / 3, kk = 3 * q + vv % 3;
        int row = Mt * 16 + (l & 15);
        int k0 = kk * 32 + (l >> 4) * 8;
        f16x8 v;
#pragma unroll
        for (int i = 0; i < 8; ++i) v[i] = (_Float16)Wih2[row * 384 + k0 + i];
        wih2f[t2] = v;
    }
}

// ---------------------------------------------------------------------------
// gru1_scan: 16 blocks = 4 groups (16 batches each) x 4 j-quarters.
// 12 waves: (jc 0..5) x (kh 0..1 K-split). Weights register-resident as MFMA
// A-fragments; per-step GEMM M=(r|z|hn|xn per 16 j) N=16 batches K=416.
// kh1 writes K-partials to LDS; kh0 reduces + pointwise + exchange-store;
// kh1 concurrently polls remote h from MALL (tagged u64 = 2 fp16 + tag).
// xp2 (GRU2 input proj) = 1 extra MFMA on waves v<9, k-partial atomicAdd.
// ---------------------------------------------------------------------------
__global__ __launch_bounds__(768) void gru1_scan(
    const float* __restrict__ x, const float* __restrict__ h1_0,
    const float* __restrict__ bih1, const float* __restrict__ bhh1,
    const f16x8* __restrict__ whhA, const f16x8* __restrict__ wih2f,
    float* __restrict__ sxp2g, u64_t* __restrict__ exch,
    float* __restrict__ h1f_o) {
    const int bid = blockIdx.x;
    const int g = bid >> 2, q = bid & 3;
    const int tid = threadIdx.x;
    const int v = tid >> 6, l = tid & 63;
    const int jc = v >> 1, kh = v & 1;
    const int rg = l >> 4, b = l & 15;
    const int j0 = q * 96 + jc * 16 + rg * 4;

    __shared__ __align__(16) _Float16 hbuf[2][6784];  // [buf][b*424 + k]
    __shared__ __align__(16) float part[6528];        // (jc*64+l)*17 + 16 vals

    // ---- A fragments into registers ----
    f16x8 A[20];
    {
        const f16x8* ap = whhA + (size_t)(((q * 6 + jc) * 2 + kh) * 20) * 64 + l;
#pragma unroll
        for (int c = 0; c < 20; ++c) A[c] = ap[c * 64];
    }
    const bool xw = (v < 9);
    const int ktx = 3 * q + v % 3, Mtx = v / 3;
    f16x8 Ax;
    if (xw) Ax = wih2f[(q * 9 + v) * 64 + l];

    // ---- biases + own h state (kh0 lanes own (j0..j0+3, b)) ----
    float bR[4], bZ[4], bXN[4], bHN[4], hp[4];
    if (kh == 0) {
#pragma unroll
        for (int i = 0; i < 4; ++i) {
            int j = j0 + i;
            bR[i]  = bih1[j] + bhh1[j];
            bZ[i]  = bih1[384 + j] + bhh1[384 + j];
            bXN[i] = bih1[768 + j];
            bHN[i] = bhh1[768 + j];
            hp[i]  = h1_0[(size_t)(g * 16 + b) * 384 + j];
        }
    }

    // ---- poll address tables (kh1) ----
    int wo[6], lo[6];
    const int p = jc * 64 + l;
    if (kh == 1) {
#pragma unroll
        for (int k = 0; k < 6; ++k) {
            int idx = p + 384 * k;
            int r_ = idx >> 4, b2 = idx & 15;
            int jwr = (q * 48 + 48 + r_) % 192;
            wo[k] = jwr * 16 + b2;
            lo[k] = b2 * 424 + jwr * 2;
        }
    }
    const int bx_ = p / 20, xi_ = p % 20;  // x-staging role (kh1, p<320)

    // ---- prologue: fill hbuf[0] with h_0 | x_0 | pad; zero hbuf[1] ----
    for (int idx = tid; idx < 6784; idx += 768) {
        int bb = idx / 424, k = idx % 424;
        float val = 0.f;
        if (k < 384) val = h1_0[(size_t)(g * 16 + bb) * 384 + k];
        else if (k < 404) val = x[(size_t)(g * 16 + bb) * 40960 + (k - 384)];
        hbuf[0][idx] = (_Float16)val;
        hbuf[1][idx] = (_Float16)0.f;
    }
    u64_t* exg = exch + (size_t)g * 6144;
    __syncthreads();

    for (int t = 0; t < 2048; ++t) {
        const int cur = t & 1, nxt = cur ^ 1;
        const _Float16* hc = hbuf[cur];
        _Float16* hn = hbuf[nxt];
        const unsigned tag = (unsigned)(t + 1);
        u64_t* exw = exg + ((t + 1) & 1) * 3072;

        // x prefetch for t+1 (kh1 staging lanes)
        float xreg = 0.f;
        if (kh == 1 && p < 320 && t + 1 < 2048)
            xreg = x[(size_t)(g * 16 + bx_) * 40960 + (t + 1) * 20 + xi_];

        // ---- MFMAs ----
        f32x4 aR{0.f, 0.f, 0.f, 0.f}, aZ{0.f, 0.f, 0.f, 0.f};
        f32x4 aN{0.f, 0.f, 0.f, 0.f}, aX{0.f, 0.f, 0.f, 0.f};
        if (kh == 0) {
#pragma unroll
            for (int ki = 0; ki < 7; ++ki) {
                f16x8 Bf = *(const f16x8*)(hc + b * 424 + ki * 32 + rg * 8);
                aR = mfma16(A[ki], Bf, aR);
                aZ = mfma16(A[7 + ki], Bf, aZ);
                if (ki < 6) aN = mfma16(A[14 + ki], Bf, aN);
            }
        } else {
#pragma unroll
            for (int ki = 0; ki < 7; ++ki) {
                f16x8 Bf = *(const f16x8*)(hc + b * 424 + (6 + ki) * 32 + rg * 8);
                if (ki > 0) {
                    aR = mfma16(A[ki - 1], Bf, aR);
                    aZ = mfma16(A[5 + ki], Bf, aZ);
                }
                if (ki < 6) aN = mfma16(A[12 + ki], Bf, aN);
                if (ki == 6) aX = mfma16(A[18], Bf, aX);
            }
        }

        // ---- xp2 for time index t-1 (projects h_t = y1[t-1]) ----
        if (xw && t > 0) {
            f16x8 Bx = *(const f16x8*)(hc + b * 424 + ktx * 32 + rg * 8);
            f32x4 px = mfma16(Ax, Bx, (f32x4){0.f, 0.f, 0.f, 0.f});
            float* dst = sxp2g + ((size_t)(g * 16 + b) * 2048 + (t - 1)) * 48 +
                         Mtx * 16 + rg * 4;
#pragma unroll
            for (int i = 0; i < 4; ++i) atomicAdd(dst + i, px[i]);
        }

        // ---- kh1: publish K-partials ----
        if (kh == 1) {
            float* pp = part + (jc * 64 + l) * 17;
#pragma unroll
            for (int i = 0; i < 4; ++i) {
                pp[i] = aR[i]; pp[4 + i] = aZ[i];
                pp[8 + i] = aN[i]; pp[12 + i] = aX[i];
            }
        }
        __syncthreads();  // S1

        if (kh == 0) {
            // ---- reduce + pointwise + store own h ----
            const float* pp = part + (jc * 64 + l) * 17;
            _Float16 hh[4];
#pragma unroll
            for (int i = 0; i < 4; ++i) {
                float sR = aR[i] + pp[i];
                float sZ = aZ[i] + pp[4 + i];
                float sN = aN[i] + pp[8 + i];
                float sX = aX[i] + pp[12 + i];
                float r = sigmoidf_(sR + bR[i]);
                float z = sigmoidf_(sZ + bZ[i]);
                float n = tanhf_(sX + bXN[i] + r * (sN + bHN[i]));
                float h = n + z * (hp[i] - n);
                hp[i] = h;
                hh[i] = (_Float16)h;
            }
            FP16U u0, u1, u2, u3;
            u0.h = hh[0]; u1.h = hh[1]; u2.h = hh[2]; u3.h = hh[3];
            unsigned w01 = (unsigned)u0.u | ((unsigned)u1.u << 16);
            unsigned w23 = (unsigned)u2.u | ((unsigned)u3.u << 16);
            u64_t e0 = (u64_t)w01 | ((u64_t)tag << 32);
            u64_t e1 = (u64_t)w23 | ((u64_t)tag << 32);
            int wA = (j0 >> 1) * 16 + b;
            __hip_atomic_store(exw + wA, e0, __ATOMIC_RELAXED,
                               __HIP_MEMORY_SCOPE_AGENT);
            __hip_atomic_store(exw + wA + 16, e1, __ATOMIC_RELAXED,
                               __HIP_MEMORY_SCOPE_AGENT);
            f16x4 hq; hq[0] = hh[0]; hq[1] = hh[1]; hq[2] = hh[2]; hq[3] = hh[3];
            *(f16x4*)(hn + b * 424 + j0) = hq;
        } else {
            // ---- stage x_{t+1}; poll remote h into hbuf[nxt] ----
            if (p < 320 && t + 1 < 2048)
                hn[bx_ * 424 + 384 + xi_] = (_Float16)xreg;
            u64_t vv0, vv1, vv2, vv3, vv4, vv5;
            bool ok;
            do {
                vv0 = __hip_atomic_load(exw + wo[0], __ATOMIC_RELAXED, __HIP_MEMORY_SCOPE_AGENT);
                vv1 = __hip_atomic_load(exw + wo[1], __ATOMIC_RELAXED, __HIP_MEMORY_SCOPE_AGENT);
                vv2 = __hip_atomic_load(exw + wo[2], __ATOMIC_RELAXED, __HIP_MEMORY_SCOPE_AGENT);
                vv3 = __hip_atomic_load(exw + wo[3], __ATOMIC_RELAXED, __HIP_MEMORY_SCOPE_AGENT);
                vv4 = __hip_atomic_load(exw + wo[4], __ATOMIC_RELAXED, __HIP_MEMORY_SCOPE_AGENT);
                vv5 = __hip_atomic_load(exw + wo[5], __ATOMIC_RELAXED, __HIP_MEMORY_SCOPE_AGENT);
                ok = ((unsigned)(vv0 >> 32) == tag) & ((unsigned)(vv1 >> 32) == tag) &
                     ((unsigned)(vv2 >> 32) == tag) & ((unsigned)(vv3 >> 32) == tag) &
                     ((unsigned)(vv4 >> 32) == tag) & ((unsigned)(vv5 >> 32) == tag);
            } while (!ok);
            *(unsigned*)(hn + lo[0]) = (unsigned)vv0;
            *(unsigned*)(hn + lo[1]) = (unsigned)vv1;
            *(unsigned*)(hn + lo[2]) = (unsigned)vv2;
            *(unsigned*)(hn + lo[3]) = (unsigned)vv3;
            *(unsigned*)(hn + lo[4]) = (unsigned)vv4;
            *(unsigned*)(hn + lo[5]) = (unsigned)vv5;
        }
        __syncthreads();  // S2: hbuf[nxt] = h_{t+1} | x_{t+1} complete
    }

    // ---- epilogue: xp2 for time 2047 (projects h_2048, now in hbuf[0]) ----
    if (xw) {
        const _Float16* hc = hbuf[0];
        f16x8 Bx = *(const f16x8*)(hc + b * 424 + ktx * 32 + rg * 8);
        f32x4 px = mfma16(Ax, Bx, (f32x4){0.f, 0.f, 0.f, 0.f});
        float* dst = sxp2g + ((size_t)(g * 16 + b) * 2048 + 2047) * 48 +
                     Mtx * 16 + rg * 4;
#pragma unroll
        for (int i = 0; i < 4; ++i) atomicAdd(dst + i, px[i]);
    }
    if (kh == 0) {
        float4 hv = make_float4(hp[0], hp[1], hp[2], hp[3]);
        *(float4*)(h1f_o + (size_t)(g * 16 + b) * 384 + j0) = hv;
    }
}

// ---------------------------------------------------------------------------
// Tail: GRU2+ReLU+FC forward (from sxp2), then GRU3 reverse. One wave per
// batch; recurrent state replicated per-lane, re-broadcast via one LDS write
// + broadcast reads (3 shfl/step instead of 35-43).
// ---------------------------------------------------------------------------
__global__ __launch_bounds__(64) void tail_scan(
    const float* __restrict__ sxp2g, const float* __restrict__ h2_0,
    const float* __restrict__ h3_0,
    const float* __restrict__ Whh2, const float* __restrict__ bih2,
    const float* __restrict__ bhh2,
    const float* __restrict__ Wfc, const float* __restrict__ bfc,
    const float* __restrict__ Wih3, const float* __restrict__ Whh3,
    const float* __restrict__ bih3, const float* __restrict__ bhh3,
    float* __restrict__ xmid, float* __restrict__ xout,
    float* __restrict__ h2f_o, float* __restrict__ h3f_o) {
    const int b = blockIdx.x;
    const int l = threadIdx.x;

    __shared__ __align__(16) float hs[32];  // state broadcast staging

    // ================= loop 1: GRU2 + ReLU + FC + 2*tanh =================
    float w2r[16]; float bx2 = 0.f, bh2 = 0.f;
    if (l < 48) {
#pragma unroll
        for (int k = 0; k < 16; ++k) w2r[k] = Whh2[l * 16 + k];
        bx2 = bih2[l]; bh2 = bhh2[l];
    }
    float wfc[16]; float bf = 0.f;
    if (l < 20) {
#pragma unroll
        for (int k = 0; k < 16; ++k) wfc[k] = Wfc[l * 16 + k];
        bf = bfc[l];
    }
    float h2all[16];
    {
        const float4* hp = (const float4*)(h2_0 + b * 16);
#pragma unroll
        for (int c = 0; c < 4; ++c) {
            float4 v = hp[c];
            h2all[c * 4 + 0] = v.x; h2all[c * 4 + 1] = v.y;
            h2all[c * 4 + 2] = v.z; h2all[c * 4 + 3] = v.w;
        }
    }
    float hown = (l < 16) ? h2_0[b * 16 + l] : 0.f;

    float* xm = xmid + (size_t)b * 40960;
    const float* sx = sxp2g + (size_t)b * 98304;

    float pre[8];
#pragma unroll
    for (int i = 0; i < 8; ++i) pre[i] = (l < 48) ? sx[i * 48 + l] : 0.f;

    for (int tg = 0; tg < 256; ++tg) {
#pragma unroll
        for (int tq = 0; tq < 8; ++tq) {
            const int t = tg * 8 + tq;
            float ax = pre[tq] + bx2;
            if (l < 48 && t + 8 < 2048) pre[tq] = sx[(size_t)(t + 8) * 48 + l];
            float a0 = 0.f, a1 = 0.f;
#pragma unroll
            for (int k = 0; k < 8; ++k) {
                a0 = __builtin_fmaf(h2all[k], w2r[k], a0);
                a1 = __builtin_fmaf(h2all[8 + k], w2r[8 + k], a1);
            }
            float ah = bh2 + a0 + a1;
            float s_   = ax + ah;
            float zpre = __shfl(s_, (16 + l) & 63);
            float xn3  = __shfl(ax, (32 + l) & 63);
            float ghn  = __shfl(ah, (32 + l) & 63);
            float r2 = sigmoidf_(s_);
            float z2 = sigmoidf_(zpre);
            float n2 = tanhf_(xn3 + r2 * ghn);
            float h2n = (1.f - z2) * n2 + z2 * hown;
            if (l < 16) { hown = h2n; hs[l] = h2n; }
            __builtin_amdgcn_wave_barrier();
            {
                const float4* hv = (const float4*)hs;
#pragma unroll
                for (int c = 0; c < 4; ++c) {
                    float4 v = hv[c];
                    h2all[c * 4 + 0] = v.x; h2all[c * 4 + 1] = v.y;
                    h2all[c * 4 + 2] = v.z; h2all[c * 4 + 3] = v.w;
                }
            }
            float f0 = 0.f, f1 = 0.f;
#pragma unroll
            for (int k = 0; k < 8; ++k) {
                f0 = __builtin_fmaf(fmaxf(h2all[k], 0.f), wfc[k], f0);
                f1 = __builtin_fmaf(fmaxf(h2all[8 + k], 0.f), wfc[8 + k], f1);
            }
            float a = bf + f0 + f1;
            if (l < 20) xm[t * 20 + l] = 2.f * tanhf_(a);
        }
    }
    if (l < 16) h2f_o[b * 16 + l] = hown;

    // ================= loop 2: GRU3 over reversed xmid =================
    float wi3[20], wh3[20]; float bx3 = 0.f, bh3 = 0.f;
    if (l < 60) {
#pragma unroll
        for (int k = 0; k < 20; ++k) {
            wi3[k] = Wih3[l * 20 + k];
            wh3[k] = Whh3[l * 20 + k];
        }
        bx3 = bih3[l]; bh3 = bhh3[l];
    }
    float h3all[20];
    {
        const float4* hp = (const float4*)(h3_0 + b * 20);
#pragma unroll
        for (int c = 0; c < 5; ++c) {
            float4 v = hp[c];
            h3all[c * 4 + 0] = v.x; h3all[c * 4 + 1] = v.y;
            h3all[c * 4 + 2] = v.z; h3all[c * 4 + 3] = v.w;
        }
    }
    float h3own = (l < 20) ? h3_0[b * 20 + l] : 0.f;
    float* xo = xout + (size_t)b * 40960;

    float4 px[4][5];
#pragma unroll
    for (int i = 0; i < 4; ++i) {
        const float4* xr = (const float4*)(xm + (size_t)(2047 - i) * 20);
#pragma unroll
        for (int c = 0; c < 5; ++c) px[i][c] = xr[c];
    }

    for (int tg = 0; tg < 512; ++tg) {
#pragma unroll
        for (int tq = 0; tq < 4; ++tq) {
            const int t = 2047 - (tg * 4 + tq);
            float xv[20];
#pragma unroll
            for (int c = 0; c < 5; ++c) {
                float4 v = px[tq][c];
                xv[c * 4 + 0] = v.x; xv[c * 4 + 1] = v.y;
                xv[c * 4 + 2] = v.z; xv[c * 4 + 3] = v.w;
            }
            if (t - 4 >= 0) {
                const float4* xr = (const float4*)(xm + (size_t)(t - 4) * 20);
#pragma unroll
                for (int c = 0; c < 5; ++c) px[tq][c] = xr[c];
            }
            float x0 = 0.f, x1 = 0.f, g0 = 0.f, g1 = 0.f;
#pragma unroll
            for (int k = 0; k < 10; ++k) {
                x0 = __builtin_fmaf(xv[k], wi3[k], x0);
                x1 = __builtin_fmaf(xv[10 + k], wi3[10 + k], x1);
                g0 = __builtin_fmaf(h3all[k], wh3[k], g0);
                g1 = __builtin_fmaf(h3all[10 + k], wh3[10 + k], g1);
            }
            float ax = bx3 + x0 + x1;
            float ah = bh3 + g0 + g1;
            float s_   = ax + ah;
            float zpre = __shfl(s_, (20 + l) & 63);
            float xn_  = __shfl(ax, (40 + l) & 63);
            float ghn  = __shfl(ah, (40 + l) & 63);
            float r = sigmoidf_(s_);
            float z = sigmoidf_(zpre);
            float n = tanhf_(xn_ + r * ghn);
            float hn = (1.f - z) * n + z * h3own;
            if (l < 20) {
                h3own = hn;
                hs[l] = hn;
                xo[(size_t)(2047 - t) * 20 + l] = tanhf_(hn);
            }
            __builtin_amdgcn_wave_barrier();
#pragma unroll
            for (int c = 0; c < 5; ++c) {
                float4 v = ((const float4*)hs)[c];
                h3all[c * 4 + 0] = v.x; h3all[c * 4 + 1] = v.y;
                h3all[c * 4 + 2] = v.z; h3all[c * 4 + 3] = v.w;
            }
        }
    }
    if (l < 20) h3f_o[b * 20 + l] = h3own;
}

extern "C" void kernel_launch(void* const* d_in, const int* in_sizes, int n_in,
                              void* d_out, int out_size, void* d_ws, size_t ws_size,
                              hipStream_t stream) {
    const float* x    = (const float*)d_in[0];
    const float* h1   = (const float*)d_in[1];
    const float* h2   = (const float*)d_in[2];
    const float* h3   = (const float*)d_in[3];
    const float* Wih1 = (const float*)d_in[4];
    const float* Whh1 = (const float*)d_in[5];
    const float* bih1 = (const float*)d_in[6];
    const float* bhh1 = (const float*)d_in[7];
    const float* Wih2 = (const float*)d_in[8];
    const float* Whh2 = (const float*)d_in[9];
    const float* bih2 = (const float*)d_in[10];
    const float* bhh2 = (const float*)d_in[11];
    const float* Wih3 = (const float*)d_in[12];
    const float* Whh3 = (const float*)d_in[13];
    const float* bih3 = (const float*)d_in[14];
    const float* bhh3 = (const float*)d_in[15];
    const float* Wfc  = (const float*)d_in[16];
    const float* bfc  = (const float*)d_in[17];

    float* out  = (float*)d_out;
    float* xmid = out;                  // (64,2048,20)
    float* xout = out + 2621440;        // (64,2048,20)
    float* h1f  = out + 5242880;        // (64,384)
    float* h2f  = out + 5267456;        // (64,16)
    float* h3f  = out + 5268480;        // (64,20)

    char* ws = (char*)d_ws;
    _Float16* wsh  = (_Float16*)ws;
    float*    sxp2 = (float*)(ws + 1048576);
    u64_t*    exch = (u64_t*)(ws + 26214400);

    hipMemsetAsync(exch, 0, 196608, stream);     // tags := 0
    hipMemsetAsync(sxp2, 0, 25165824, stream);   // xp2 accumulators := 0
    pack_weights<<<249, 256, 0, stream>>>(Whh1, Wih1, Wih2, wsh);
    gru1_scan<<<16, 768, 0, stream>>>(x, h1, bih1, bhh1,
                                      (const f16x8*)wsh,
                                      (const f16x8*)(wsh + 491520),
                                      sxp2, exch, h1f);
    tail_scan<<<64, 64, 0, stream>>>(sxp2, h2, h3,
                                     Whh2, bih2, bhh2, Wfc, bfc,
                                     Wih3, Whh3, bih3, bhh3,
                                     xmid, xout, h2f, h3f);
}

// Round 3
// 7553.661 us; speedup vs baseline: 1.0908x; 1.0908x over previous
//
#include <hip/hip_runtime.h>

typedef _Float16 f16x8 __attribute__((ext_vector_type(8)));
typedef _Float16 f16x4 __attribute__((ext_vector_type(4)));
typedef float f32x4 __attribute__((ext_vector_type(4)));
typedef unsigned long long u64_t;

union FP16U { _Float16 h; unsigned short u; };

__device__ __forceinline__ float sigmoidf_(float x) {
    return __builtin_amdgcn_rcpf(1.f + __expf(-x));
}

__device__ __forceinline__ float tanhf_(float x) {
    float a = fabsf(x);
    float e = __expf(-2.f * a);
    float r = (1.f - e) * __builtin_amdgcn_rcpf(1.f + e);
    return copysignf(r, x);
}

__device__ __forceinline__ f32x4 mfma16(f16x8 a, f16x8 b, f32x4 c) {
    return __builtin_amdgcn_mfma_f32_16x16x32_f16(a, b, c, 0, 0, 0);
}

// ---------------------------------------------------------------------------
// ws layout (bytes):
//   0        : whhA   61440 f16x8 A-fragments (983040 B)
//   983040   : wih2f  2304 f16x8 A-fragments, frag = (Mt*12+kt)*64+lane (36864 B)
//   1048576  : sxp2   64*2048*48 f32 (25165824 B) — plain stores, each elem once
//   26214400 : exch   4 groups * 2 bufs * 3072 u64 tagged h-pairs (196608 B)
// ---------------------------------------------------------------------------
// A-fragment semantics (mfma_f32_16x16x32_f16):
//   lane l: A row = (l&15), k = (l>>4)*8 + i ; B col = (l&15), same k
//   lane l: C row = (l>>4)*4 + i, col = (l&15)
// K layout (416): k<384 -> h[k]; 384..403 -> x[k-384]; 404..415 -> 0 pad.
// kh0 fslots: 0..6 R kt0..6 | 7..13 Z kt0..6 | 14..19 HN kt0..5
// kh1 fslots: 0..5 R kt7..12 | 6..11 Z kt7..12 | 12..17 HN kt6..11 | 18 XN kt12

__global__ void pack_weights(const float* __restrict__ Whh1,
                             const float* __restrict__ Wih1,
                             const float* __restrict__ Wih2,
                             _Float16* __restrict__ wsbase) {
    int tid = blockIdx.x * 256 + threadIdx.x;
    f16x8* whhA  = (f16x8*)wsbase;
    f16x8* wih2f = (f16x8*)(wsbase + 983040);
    if (tid < 61440) {
        int l = tid & 63, fr = tid >> 6;
        int fslot = fr % 20, w = fr / 20;
        int kh = w & 1, jq = w >> 1;
        int jc = jq % 6, q = jq / 6;
        int tile, kt;  // 0=R 1=Z 2=HN 3=XN 4=pad
        if (kh == 0) {
            if (fslot < 7)       { tile = 0; kt = fslot; }
            else if (fslot < 14) { tile = 1; kt = fslot - 7; }
            else                 { tile = 2; kt = fslot - 14; }
        } else {
            if (fslot < 6)       { tile = 0; kt = 7 + fslot; }
            else if (fslot < 12) { tile = 1; kt = 1 + fslot; }
            else if (fslot < 18) { tile = 2; kt = fslot - 6; }
            else if (fslot == 18){ tile = 3; kt = 12; }
            else                 { tile = 4; kt = 0; }
        }
        int gate = (tile == 0) ? 0 : (tile == 1) ? 1 : 2;
        int row = gate * 384 + q * 96 + jc * 16 + (l & 15);
        int k0 = kt * 32 + (l >> 4) * 8;
        f16x8 v;
#pragma unroll
        for (int i = 0; i < 8; ++i) {
            float f = 0.f;
            if (tile != 4) {
                int k = k0 + i;
                if (tile == 3) {
                    int kx = k - 384;
                    f = (kx < 20) ? Wih1[row * 20 + kx] : 0.f;
                } else if (k < 384) {
                    f = Whh1[row * 384 + k];
                } else if (tile < 2) {
                    int kx = k - 384;
                    f = (kx < 20) ? Wih1[row * 20 + kx] : 0.f;
                }
            }
            v[i] = (_Float16)f;
        }
        whhA[tid] = v;
    } else if (tid < 63744) {
        int t2 = tid - 61440;
        int l = t2 & 63, fi = t2 >> 6;   // fi = Mt*12 + kt
        int Mt = fi / 12, kt = fi % 12;
        int row = Mt * 16 + (l & 15);
        int k0 = kt * 32 + (l >> 4) * 8;
        f16x8 v;
#pragma unroll
        for (int i = 0; i < 8; ++i) v[i] = (_Float16)Wih2[row * 384 + k0 + i];
        wih2f[t2] = v;
    }
}

// ---------------------------------------------------------------------------
// gru1_scan: 16 blocks = 4 groups (16 batches each) x 4 j-quarters.
// 12 waves: (jc 0..5) x (kh 0..1 K-split). Whh1 register-resident as MFMA
// A-fragments; per-step GEMM M=(r|z|hn|xn per 16 j) N=16 batches K=416.
// h history is a 4-deep LDS ring (hhist); exchange via tagged u64 MALL
// atomics (2 fp16 + tag per word), pollers scatter into the next ring slot.
// Every 4 steps, blocks q<3 compute the GRU2 input projection (full K=384,
// one 16-out M-tile each) with 4 MFMA/wave + 3-way LDS reduce and PLAIN
// coalesced stores to sxp2 — no atomics anywhere on the data path.
// ---------------------------------------------------------------------------
__global__ __launch_bounds__(768) void gru1_scan(
    const float* __restrict__ x, const float* __restrict__ h1_0,
    const float* __restrict__ bih1, const float* __restrict__ bhh1,
    const f16x8* __restrict__ whhA, const f16x8* __restrict__ wih2f,
    float* __restrict__ sxp2g, u64_t* __restrict__ exch,
    float* __restrict__ h1f_o) {
    const int bid = blockIdx.x;
    const int g = bid >> 2, q = bid & 3;
    const int tid = threadIdx.x;
    const int v = tid >> 6, l = tid & 63;
    const int jc = v >> 1, kh = v & 1;
    const int rg = l >> 4, b = l & 15;
    const int j0 = q * 96 + jc * 16 + rg * 4;

    __shared__ __align__(16) _Float16 hhist[4][6912];  // [slot][b*432 + k]
    __shared__ __align__(16) float part[6528];         // (jc*64+l)*17 + 16
    __shared__ __align__(16) float4 xpart[768];        // [wave*64 + lane]

    // ---- Whh1/Wih1 A fragments into registers ----
    f16x8 A[20];
    {
        const f16x8* ap = whhA + (size_t)(((q * 6 + jc) * 2 + kh) * 20) * 64 + l;
#pragma unroll
        for (int c = 0; c < 20; ++c) A[c] = ap[c * 64];
    }
    // ---- xp2 A fragments (blocks q<3): wave v -> t-slot v&3, k-quarter v>>2
    const int tqx = v & 3, kqx = v >> 2;
    f16x8 Ax[4];
    if (q < 3) {
#pragma unroll
        for (int kk = 0; kk < 4; ++kk)
            Ax[kk] = wih2f[(size_t)(q * 12 + kqx * 4 + kk) * 64 + l];
    }

    // ---- biases + own h state (kh0 lanes own (j0..j0+3, b)) ----
    float bR[4], bZ[4], bXN[4], bHN[4], hp[4];
    if (kh == 0) {
#pragma unroll
        for (int i = 0; i < 4; ++i) {
            int j = j0 + i;
            bR[i]  = bih1[j] + bhh1[j];
            bZ[i]  = bih1[384 + j] + bhh1[384 + j];
            bXN[i] = bih1[768 + j];
            bHN[i] = bhh1[768 + j];
            hp[i]  = h1_0[(size_t)(g * 16 + b) * 384 + j];
        }
    }

    // ---- poll address tables (kh1) ----
    int wo[6], lo[6];
    const int p = jc * 64 + l;
    if (kh == 1) {
#pragma unroll
        for (int k = 0; k < 6; ++k) {
            int idx = p + 384 * k;
            int r_ = idx >> 4, b2 = idx & 15;
            int jwr = (q * 48 + 48 + r_) % 192;
            wo[k] = jwr * 16 + b2;
            lo[k] = b2 * 432 + jwr * 2;
        }
    }
    const int bx_ = p / 20, xi_ = p % 20;  // x-staging role (kh1, p<320)

    // ---- prologue: hhist[0] = h_0 | x_0 | pad ; slots 1..3 = 0 ----
    for (int idx = tid; idx < 27648; idx += 768) {
        int s = idx / 6912, r = idx % 6912;
        int bb = r / 432, k = r % 432;
        float val = 0.f;
        if (s == 0) {
            if (k < 384) val = h1_0[(size_t)(g * 16 + bb) * 384 + k];
            else if (k < 404) val = x[(size_t)(g * 16 + bb) * 40960 + (k - 384)];
        }
        hhist[s][bb * 432 + k] = (_Float16)val;
    }
    u64_t* exg = exch + (size_t)g * 6144;
    __syncthreads();

    for (int t = 0; t < 2048; ++t) {
        const _Float16* hc = hhist[t & 3];
        _Float16* hn = hhist[(t + 1) & 3];
        const unsigned tag = (unsigned)(t + 1);
        u64_t* exw = exg + ((t + 1) & 1) * 3072;

        // x prefetch for t+1 (kh1 staging lanes)
        float xreg = 0.f;
        if (kh == 1 && p < 320 && t + 1 < 2048)
            xreg = x[(size_t)(g * 16 + bx_) * 40960 + (t + 1) * 20 + xi_];

        // ---- gate MFMAs ----
        f32x4 aR{0.f, 0.f, 0.f, 0.f}, aZ{0.f, 0.f, 0.f, 0.f};
        f32x4 aN{0.f, 0.f, 0.f, 0.f}, aX{0.f, 0.f, 0.f, 0.f};
        if (kh == 0) {
#pragma unroll
            for (int ki = 0; ki < 7; ++ki) {
                f16x8 Bf = *(const f16x8*)(hc + b * 432 + ki * 32 + rg * 8);
                aR = mfma16(A[ki], Bf, aR);
                aZ = mfma16(A[7 + ki], Bf, aZ);
                if (ki < 6) aN = mfma16(A[14 + ki], Bf, aN);
            }
        } else {
#pragma unroll
            for (int ki = 0; ki < 7; ++ki) {
                f16x8 Bf = *(const f16x8*)(hc + b * 432 + (6 + ki) * 32 + rg * 8);
                if (ki > 0) {
                    aR = mfma16(A[ki - 1], Bf, aR);
                    aZ = mfma16(A[5 + ki], Bf, aZ);
                }
                if (ki < 6) aN = mfma16(A[12 + ki], Bf, aN);
                if (ki == 6) aX = mfma16(A[18], Bf, aX);
            }
        }

        // ---- kh1: publish K-partials ----
        if (kh == 1) {
            float* pp = part + (jc * 64 + l) * 17;
#pragma unroll
            for (int i = 0; i < 4; ++i) {
                pp[i] = aR[i]; pp[4 + i] = aZ[i];
                pp[8 + i] = aN[i]; pp[12 + i] = aX[i];
            }
        }
        __syncthreads();  // S1

        if (kh == 0) {
            // ---- reduce + pointwise + publish own h ----
            const float* pp = part + (jc * 64 + l) * 17;
            _Float16 hh[4];
#pragma unroll
            for (int i = 0; i < 4; ++i) {
                float sR = aR[i] + pp[i];
                float sZ = aZ[i] + pp[4 + i];
                float sN = aN[i] + pp[8 + i];
                float sX = aX[i] + pp[12 + i];
                float r = sigmoidf_(sR + bR[i]);
                float z = sigmoidf_(sZ + bZ[i]);
                float n = tanhf_(sX + bXN[i] + r * (sN + bHN[i]));
                float h = n + z * (hp[i] - n);
                hp[i] = h;
                hh[i] = (_Float16)h;
            }
            FP16U u0, u1, u2, u3;
            u0.h = hh[0]; u1.h = hh[1]; u2.h = hh[2]; u3.h = hh[3];
            unsigned w01 = (unsigned)u0.u | ((unsigned)u1.u << 16);
            unsigned w23 = (unsigned)u2.u | ((unsigned)u3.u << 16);
            u64_t e0 = (u64_t)w01 | ((u64_t)tag << 32);
            u64_t e1 = (u64_t)w23 | ((u64_t)tag << 32);
            int wA = (j0 >> 1) * 16 + b;
            __hip_atomic_store(exw + wA, e0, __ATOMIC_RELAXED,
                               __HIP_MEMORY_SCOPE_AGENT);
            __hip_atomic_store(exw + wA + 16, e1, __ATOMIC_RELAXED,
                               __HIP_MEMORY_SCOPE_AGENT);
            f16x4 hq; hq[0] = hh[0]; hq[1] = hh[1]; hq[2] = hh[2]; hq[3] = hh[3];
            *(f16x4*)(hn + b * 432 + j0) = hq;
        } else {
            // ---- stage x_{t+1}; poll remote h into hhist[(t+1)&3] ----
            if (p < 320 && t + 1 < 2048)
                hn[bx_ * 432 + 384 + xi_] = (_Float16)xreg;
            u64_t vv0, vv1, vv2, vv3, vv4, vv5;
            bool ok;
            do {
                vv0 = __hip_atomic_load(exw + wo[0], __ATOMIC_RELAXED, __HIP_MEMORY_SCOPE_AGENT);
                vv1 = __hip_atomic_load(exw + wo[1], __ATOMIC_RELAXED, __HIP_MEMORY_SCOPE_AGENT);
                vv2 = __hip_atomic_load(exw + wo[2], __ATOMIC_RELAXED, __HIP_MEMORY_SCOPE_AGENT);
                vv3 = __hip_atomic_load(exw + wo[3], __ATOMIC_RELAXED, __HIP_MEMORY_SCOPE_AGENT);
                vv4 = __hip_atomic_load(exw + wo[4], __ATOMIC_RELAXED, __HIP_MEMORY_SCOPE_AGENT);
                vv5 = __hip_atomic_load(exw + wo[5], __ATOMIC_RELAXED, __HIP_MEMORY_SCOPE_AGENT);
                ok = ((unsigned)(vv0 >> 32) == tag) & ((unsigned)(vv1 >> 32) == tag) &
                     ((unsigned)(vv2 >> 32) == tag) & ((unsigned)(vv3 >> 32) == tag) &
                     ((unsigned)(vv4 >> 32) == tag) & ((unsigned)(vv5 >> 32) == tag);
            } while (!ok);
            *(unsigned*)(hn + lo[0]) = (unsigned)vv0;
            *(unsigned*)(hn + lo[1]) = (unsigned)vv1;
            *(unsigned*)(hn + lo[2]) = (unsigned)vv2;
            *(unsigned*)(hn + lo[3]) = (unsigned)vv3;
            *(unsigned*)(hn + lo[4]) = (unsigned)vv4;
            *(unsigned*)(hn + lo[5]) = (unsigned)vv5;
        }
        __syncthreads();  // S2: hhist[(t+1)&3] = h_{t+1} | x_{t+1} complete

        // ---- xp2 every 4 steps: sxp2[b][t'][o] for t' = t-3..t (q<3 only).
        // h_{t'+1} lives in hhist[(t'+1)&3] = hhist[(1+tq)&3] (t ≡ 3 mod 4).
        if ((t & 3) == 3 && q < 3) {
            const _Float16* hx = hhist[(1 + tqx) & 3];
            f32x4 acc{0.f, 0.f, 0.f, 0.f};
#pragma unroll
            for (int kk = 0; kk < 4; ++kk) {
                f16x8 Bf = *(const f16x8*)(hx + b * 432 + (kqx * 4 + kk) * 32 + rg * 8);
                acc = mfma16(Ax[kk], Bf, acc);
            }
            xpart[v * 64 + l] = make_float4(acc[0], acc[1], acc[2], acc[3]);
            __syncthreads();  // S3 (q<3 blocks only; block-uniform)
            if (tid < 256) {
                int tq = tid >> 6, lr = tid & 63;
                float4 p0 = xpart[(tq) * 64 + lr];
                float4 p1 = xpart[(4 + tq) * 64 + lr];
                float4 p2 = xpart[(8 + tq) * 64 + lr];
                float4 s;
                s.x = p0.x + p1.x + p2.x;
                s.y = p0.y + p1.y + p2.y;
                s.z = p0.z + p1.z + p2.z;
                s.w = p0.w + p1.w + p2.w;
                *(float4*)(sxp2g +
                    ((size_t)(g * 16 + (lr & 15)) * 2048 + (t - 3 + tq)) * 48 +
                    q * 16 + (lr >> 4) * 4) = s;
            }
        }
    }

    if (kh == 0) {
        float4 hv = make_float4(hp[0], hp[1], hp[2], hp[3]);
        *(float4*)(h1f_o + (size_t)(g * 16 + b) * 384 + j0) = hv;
    }
}

// ---------------------------------------------------------------------------
// Tail: GRU2+ReLU+FC forward (from sxp2), then GRU3 reverse. One wave per
// batch; recurrent state replicated per-lane, re-broadcast via one LDS write
// + broadcast reads (3 shfl/step instead of 35-43).
// ---------------------------------------------------------------------------
__global__ __launch_bounds__(64) void tail_scan(
    const float* __restrict__ sxp2g, const float* __restrict__ h2_0,
    const float* __restrict__ h3_0,
    const float* __restrict__ Whh2, const float* __restrict__ bih2,
    const float* __restrict__ bhh2,
    const float* __restrict__ Wfc, const float* __restrict__ bfc,
    const float* __restrict__ Wih3, const float* __restrict__ Whh3,
    const float* __restrict__ bih3, const float* __restrict__ bhh3,
    float* __restrict__ xmid, float* __restrict__ xout,
    float* __restrict__ h2f_o, float* __restrict__ h3f_o) {
    const int b = blockIdx.x;
    const int l = threadIdx.x;

    __shared__ __align__(16) float hs[32];  // state broadcast staging

    // ================= loop 1: GRU2 + ReLU + FC + 2*tanh =================
    float w2r[16]; float bx2 = 0.f, bh2 = 0.f;
    if (l < 48) {
#pragma unroll
        for (int k = 0; k < 16; ++k) w2r[k] = Whh2[l * 16 + k];
        bx2 = bih2[l]; bh2 = bhh2[l];
    }
    float wfc[16]; float bf = 0.f;
    if (l < 20) {
#pragma unroll
        for (int k = 0; k < 16; ++k) wfc[k] = Wfc[l * 16 + k];
        bf = bfc[l];
    }
    float h2all[16];
    {
        const float4* hp = (const float4*)(h2_0 + b * 16);
#pragma unroll
        for (int c = 0; c < 4; ++c) {
            float4 v = hp[c];
            h2all[c * 4 + 0] = v.x; h2all[c * 4 + 1] = v.y;
            h2all[c * 4 + 2] = v.z; h2all[c * 4 + 3] = v.w;
        }
    }
    float hown = (l < 16) ? h2_0[b * 16 + l] : 0.f;

    float* xm = xmid + (size_t)b * 40960;
    const float* sx = sxp2g + (size_t)b * 98304;

    float pre[8];
#pragma unroll
    for (int i = 0; i < 8; ++i) pre[i] = (l < 48) ? sx[i * 48 + l] : 0.f;

    for (int tg = 0; tg < 256; ++tg) {
#pragma unroll
        for (int tq = 0; tq < 8; ++tq) {
            const int t = tg * 8 + tq;
            float ax = pre[tq] + bx2;
            if (l < 48 && t + 8 < 2048) pre[tq] = sx[(size_t)(t + 8) * 48 + l];
            float a0 = 0.f, a1 = 0.f;
#pragma unroll
            for (int k = 0; k < 8; ++k) {
                a0 = __builtin_fmaf(h2all[k], w2r[k], a0);
                a1 = __builtin_fmaf(h2all[8 + k], w2r[8 + k], a1);
            }
            float ah = bh2 + a0 + a1;
            float s_   = ax + ah;
            float zpre = __shfl(s_, (16 + l) & 63);
            float xn3  = __shfl(ax, (32 + l) & 63);
            float ghn  = __shfl(ah, (32 + l) & 63);
            float r2 = sigmoidf_(s_);
            float z2 = sigmoidf_(zpre);
            float n2 = tanhf_(xn3 + r2 * ghn);
            float h2n = (1.f - z2) * n2 + z2 * hown;
            if (l < 16) { hown = h2n; hs[l] = h2n; }
            __builtin_amdgcn_wave_barrier();
            {
                const float4* hv = (const float4*)hs;
#pragma unroll
                for (int c = 0; c < 4; ++c) {
                    float4 v = hv[c];
                    h2all[c * 4 + 0] = v.x; h2all[c * 4 + 1] = v.y;
                    h2all[c * 4 + 2] = v.z; h2all[c * 4 + 3] = v.w;
                }
            }
            float f0 = 0.f, f1 = 0.f;
#pragma unroll
            for (int k = 0; k < 8; ++k) {
                f0 = __builtin_fmaf(fmaxf(h2all[k], 0.f), wfc[k], f0);
                f1 = __builtin_fmaf(fmaxf(h2all[8 + k], 0.f), wfc[8 + k], f1);
            }
            float a = bf + f0 + f1;
            if (l < 20) xm[t * 20 + l] = 2.f * tanhf_(a);
        }
    }
    if (l < 16) h2f_o[b * 16 + l] = hown;

    // ================= loop 2: GRU3 over reversed xmid =================
    float wi3[20], wh3[20]; float bx3 = 0.f, bh3 = 0.f;
    if (l < 60) {
#pragma unroll
        for (int k = 0; k < 20; ++k) {
            wi3[k] = Wih3[l * 20 + k];
            wh3[k] = Whh3[l * 20 + k];
        }
        bx3 = bih3[l]; bh3 = bhh3[l];
    }
    float h3all[20];
    {
        const float4* hp = (const float4*)(h3_0 + b * 20);
#pragma unroll
        for (int c = 0; c < 5; ++c) {
            float4 v = hp[c];
            h3all[c * 4 + 0] = v.x; h3all[c * 4 + 1] = v.y;
            h3all[c * 4 + 2] = v.z; h3all[c * 4 + 3] = v.w;
        }
    }
    float h3own = (l < 20) ? h3_0[b * 20 + l] : 0.f;
    float* xo = xout + (size_t)b * 40960;

    float4 px[4][5];
#pragma unroll
    for (int i = 0; i < 4; ++i) {
        const float4* xr = (const float4*)(xm + (size_t)(2047 - i) * 20);
#pragma unroll
        for (int c = 0; c < 5; ++c) px[i][c] = xr[c];
    }

    for (int tg = 0; tg < 512; ++tg) {
#pragma unroll
        for (int tq = 0; tq < 4; ++tq) {
            const int t = 2047 - (tg * 4 + tq);
            float xv[20];
#pragma unroll
            for (int c = 0; c < 5; ++c) {
                float4 v = px[tq][c];
                xv[c * 4 + 0] = v.x; xv[c * 4 + 1] = v.y;
                xv[c * 4 + 2] = v.z; xv[c * 4 + 3] = v.w;
            }
            if (t - 4 >= 0) {
                const float4* xr = (const float4*)(xm + (size_t)(t - 4) * 20);
#pragma unroll
                for (int c = 0; c < 5; ++c) px[tq][c] = xr[c];
            }
            float x0 = 0.f, x1 = 0.f, g0 = 0.f, g1 = 0.f;
#pragma unroll
            for (int k = 0; k < 10; ++k) {
                x0 = __builtin_fmaf(xv[k], wi3[k], x0);
                x1 = __builtin_fmaf(xv[10 + k], wi3[10 + k], x1);
                g0 = __builtin_fmaf(h3all[k], wh3[k], g0);
                g1 = __builtin_fmaf(h3all[10 + k], wh3[10 + k], g1);
            }
            float ax = bx3 + x0 + x1;
            float ah = bh3 + g0 + g1;
            float s_   = ax + ah;
            float zpre = __shfl(s_, (20 + l) & 63);
            float xn_  = __shfl(ax, (40 + l) & 63);
            float ghn  = __shfl(ah, (40 + l) & 63);
            float r = sigmoidf_(s_);
            float z = sigmoidf_(zpre);
            float n = tanhf_(xn_ + r * ghn);
            float hn = (1.f - z) * n + z * h3own;
            if (l < 20) {
                h3own = hn;
                hs[l] = hn;
                xo[(size_t)(2047 - t) * 20 + l] = tanhf_(hn);
            }
            __builtin_amdgcn_wave_barrier();
#pragma unroll
            for (int c = 0; c < 5; ++c) {
                float4 v = ((const float4*)hs)[c];
                h3all[c * 4 + 0] = v.x; h3all[c * 4 + 1] = v.y;
                h3all[c * 4 + 2] = v.z; h3all[c * 4 + 3] = v.w;
            }
        }
    }
    if (l < 20) h3f_o[b * 20 + l] = h3own;
}

extern "C" void kernel_launch(void* const* d_in, const int* in_sizes, int n_in,
                              void* d_out, int out_size, void* d_ws, size_t ws_size,
                              hipStream_t stream) {
    const float* x    = (const float*)d_in[0];
    const float* h1   = (const float*)d_in[1];
    const float* h2   = (const float*)d_in[2];
    const float* h3   = (const float*)d_in[3];
    const float* Wih1 = (const float*)d_in[4];
    const float* Whh1 = (const float*)d_in[5];
    const float* bih1 = (const float*)d_in[6];
    const float* bhh1 = (const float*)d_in[7];
    const float* Wih2 = (const float*)d_in[8];
    const float* Whh2 = (const float*)d_in[9];
    const float* bih2 = (const float*)d_in[10];
    const float* bhh2 = (const float*)d_in[11];
    const float* Wih3 = (const float*)d_in[12];
    const float* Whh3 = (const float*)d_in[13];
    const float* bih3 = (const float*)d_in[14];
    const float* bhh3 = (const float*)d_in[15];
    const float* Wfc  = (const float*)d_in[16];
    const float* bfc  = (const float*)d_in[17];

    float* out  = (float*)d_out;
    float* xmid = out;                  // (64,2048,20)
    float* xout = out + 2621440;        // (64,2048,20)
    float* h1f  = out + 5242880;        // (64,384)
    float* h2f  = out + 5267456;        // (64,16)
    float* h3f  = out + 5268480;        // (64,20)

    char* ws = (char*)d_ws;
    _Float16* wsh  = (_Float16*)ws;
    float*    sxp2 = (float*)(ws + 1048576);
    u64_t*    exch = (u64_t*)(ws + 26214400);

    hipMemsetAsync(exch, 0, 196608, stream);  // tags := 0 (never matches 1..2048)
    pack_weights<<<249, 256, 0, stream>>>(Whh1, Wih1, Wih2, wsh);
    gru1_scan<<<16, 768, 0, stream>>>(x, h1, bih1, bhh1,
                                      (const f16x8*)wsh,
                                      (const f16x8*)(wsh + 983040),
                                      sxp2, exch, h1f);
    tail_scan<<<64, 64, 0, stream>>>(sxp2, h2, h3,
                                     Whh2, bih2, bhh2, Wfc, bfc,
                                     Wih3, Whh3, bih3, bhh3,
                                     xmid, xout, h2f, h3f);
}